// Round 7
// baseline (457.416 us; speedup 1.0000x reference)
//
#include <hip/hip_runtime.h>
#include <hip/hip_bf16.h>

constexpr int kB   = 32;
constexpr int kC   = 256;
constexpr int kHW  = 4096;   // 64*64
constexpr int kC4  = 64;
constexpr int kGC  = 16;
constexpr int kNID = 80;     // 128 - 3*16

__device__ __forceinline__ float gelu_exact(float x) {
    return 0.5f * x * (1.0f + erff(x * 0.70710678118654752440f));
}

__device__ __forceinline__ float4 gelu4(float4 v) {
    return make_float4(gelu_exact(v.x), gelu_exact(v.y), gelu_exact(v.z), gelu_exact(v.w));
}

// ---------------- Kernel 0: init qp + qkbuf accumulators (ws is poisoned 0xAA) ----------------
// kp needs no init: conv1x1 head-1 blocks write every kp element directly.
// (Exact r5-verified structure.)
__global__ __launch_bounds__(256) void init_kernel(float4* __restrict__ qp, float4* __restrict__ qkb)
{
    int bid = blockIdx.x;
    if (bid < 2048) {
        size_t i = (size_t)bid * 256 + threadIdx.x;           // 524288 float4 = qp
        qp[i] = make_float4(0.f, 0.f, 0.f, 0.f);
    } else {
        size_t i = (size_t)(bid - 2048) * 256 + threadIdx.x;  // 32768 float4 = qkbuf
        qkb[i] = make_float4(0.f, 0.f, 0.f, 0.f);
    }
}

// ---------------- Kernel W: transpose w_qkvl [o][k] -> wT [k][o] (128 KB) ----------------
// Enables wave-uniform SCALAR loads of W in conv1x1 (takes W off the LDS pipe).
__global__ __launch_bounds__(256) void wt_kernel(
    const float* __restrict__ w_qkvl, float* __restrict__ wT)
{
    int k0 = blockIdx.x * 8;       // 16 blocks x 8 k
    int o  = threadIdx.x;
    #pragma unroll
    for (int r = 0; r < 8; ++r)
        wT[(size_t)(k0 + r) * 256 + o] = w_qkvl[(size_t)o * 128 + k0 + r];
}

// ---------------- Kernel 1: x1 branch (identity + 3 depthwise convs) + GELU ----------------
__global__ __launch_bounds__(256) void part1_kernel(
    const float* __restrict__ x,
    const float* __restrict__ w_hw, const float* __restrict__ b_hw,
    const float* __restrict__ w_w,  const float* __restrict__ b_w,
    const float* __restrict__ w_h,  const float* __restrict__ b_h,
    float* __restrict__ out)
{
    int bc = blockIdx.x;            // b*128 + c
    int b  = bc >> 7;
    int c  = bc & 127;
    const float4* xp4 = (const float4*)(x   + (size_t)(b * kC + c) * kHW);
    float4*       op4 = (float4*)      (out + (size_t)(b * kC + c) * kHW);
    int tid = threadIdx.x;

    if (c < kNID) {
        for (int q = tid; q < 1024; q += 256)
            op4[q] = gelu4(xp4[q]);
    } else if (c < kNID + kGC) {           // 3x3 dwconv, pad 1
        int g = c - kNID;
        float wv[9];
        #pragma unroll
        for (int j = 0; j < 9; ++j) wv[j] = w_hw[g * 9 + j];
        float bias = b_hw[g];
        for (int q = tid; q < 1024; q += 256) {
            int h = q >> 4, wq = q & 15;
            float ax = bias, ay = bias, az = bias, aw = bias;
            #pragma unroll
            for (int dy = -1; dy <= 1; ++dy) {
                int rr = h + dy;
                if ((unsigned)rr >= 64u) continue;
                int base = rr * 16;
                float  l  = (wq > 0)  ? xp4[base + wq - 1].w : 0.f;
                float4 Bv = xp4[base + wq];
                float  r  = (wq < 15) ? xp4[base + wq + 1].x : 0.f;
                float w0 = wv[(dy + 1) * 3 + 0];
                float w1 = wv[(dy + 1) * 3 + 1];
                float w2 = wv[(dy + 1) * 3 + 2];
                ax += w0 * l    + w1 * Bv.x + w2 * Bv.y;
                ay += w0 * Bv.x + w1 * Bv.y + w2 * Bv.z;
                az += w0 * Bv.y + w1 * Bv.z + w2 * Bv.w;
                aw += w0 * Bv.z + w1 * Bv.w + w2 * r;
            }
            op4[q] = make_float4(gelu_exact(ax), gelu_exact(ay), gelu_exact(az), gelu_exact(aw));
        }
    } else if (c < kNID + 2 * kGC) {       // 1x11 dwconv, pad (0,5)
        int g = c - (kNID + kGC);
        float wv[11];
        #pragma unroll
        for (int j = 0; j < 11; ++j) wv[j] = w_w[g * 11 + j];
        float bias = b_w[g];
        for (int q = tid; q < 1024; q += 256) {
            int h = q >> 4, wq = q & 15;
            int base = h * 16;
            float f[20];
            #pragma unroll
            for (int m = 0; m < 5; ++m) {
                int qq = wq + m - 2;
                float4 v;
                if ((unsigned)qq < 16u) v = xp4[base + qq];
                else                    v = make_float4(0.f, 0.f, 0.f, 0.f);
                f[4 * m + 0] = v.x; f[4 * m + 1] = v.y;
                f[4 * m + 2] = v.z; f[4 * m + 3] = v.w;
            }
            float a0 = bias, a1 = bias, a2 = bias, a3 = bias;
            #pragma unroll
            for (int m = 0; m < 11; ++m) {
                float w = wv[m];
                a0 += w * f[m + 3];
                a1 += w * f[m + 4];
                a2 += w * f[m + 5];
                a3 += w * f[m + 6];
            }
            op4[q] = make_float4(gelu_exact(a0), gelu_exact(a1), gelu_exact(a2), gelu_exact(a3));
        }
    } else {                               // 11x1 dwconv, pad (5,0)
        int g = c - (kNID + 2 * kGC);
        float wv[11];
        #pragma unroll
        for (int j = 0; j < 11; ++j) wv[j] = w_h[g * 11 + j];
        float bias = b_h[g];
        for (int q = tid; q < 1024; q += 256) {
            int h = q >> 4, wq = q & 15;
            float a0 = bias, a1 = bias, a2 = bias, a3 = bias;
            #pragma unroll
            for (int m = 0; m < 11; ++m) {
                int rr = h + m - 5;
                if ((unsigned)rr < 64u) {
                    float4 v = xp4[rr * 16 + wq];
                    float w = wv[m];
                    a0 += w * v.x; a1 += w * v.y; a2 += w * v.z; a3 += w * v.w;
                }
            }
            op4[q] = make_float4(gelu_exact(a0), gelu_exact(a1), gelu_exact(a2), gelu_exact(a3));
        }
    }
}

// ---------------- Kernel 2: 1x1 conv GEMM + GELU + pooling ----------------
// Grid: (16 px-blocks of 256 = 4 rows, 4 heads, B). Block 256 = 4 waves.
// W via wave-uniform SCALAR loads (SMEM pipe); X via 1 conflict-free ds_read_b128
// per k per lane (r5: bank conflicts = 0). T14: next K-chunk prefetched into
// registers right after the post-stage barrier -> global-load latency hides
// under the 4096-cyc FMA loop instead of sitting before the vmcnt+barrier.
__global__ __launch_bounds__(256) void conv1x1_kernel(
    const float* __restrict__ x,
    const float* __restrict__ wT, const float* __restrict__ b_qkvl,
    float* __restrict__ qp, float* __restrict__ kp,
    float* __restrict__ out)
{
    __shared__ float Xs[32 * 256];   // row k at k*256; reused as Ps[64][4][32] in epilogue
    int pb   = blockIdx.x;           // 0..15
    int p0   = pb * 256;
    int head = blockIdx.y;
    int b    = blockIdx.z;
    int t    = threadIdx.x;
    int lane = t & 63;
    int wvid = __builtin_amdgcn_readfirstlane(t >> 6);   // wave id 0..3, SGPR
    int ow   = head * 64 + wvid * 16;                    // wave's first output ch (uniform)

    const float* xbase = x + (size_t)(b * kC + 128) * kHW + p0;

    // prologue: load kc=0 chunk into registers
    float4 xreg[8];
    #pragma unroll
    for (int r = 0; r < 8; ++r) {
        int g = t + r * 256;                 // 0..2047
        int k = g >> 6, cch = g & 63;
        xreg[r] = *(const float4*)&xbase[(size_t)k * kHW + cch * 4];
    }

    float acc[16][4] = {};
    for (int kc = 0; kc < 4; ++kc) {
        // reg -> LDS (compiler inserts the vmcnt wait on xreg here)
        #pragma unroll
        for (int r = 0; r < 8; ++r) {
            int g = t + r * 256;
            int k = g >> 6, cch = g & 63;
            *(float4*)&Xs[k * 256 + cch * 4] = xreg[r];
        }
        __syncthreads();
        // issue next chunk's global loads; latency hidden under the FMA loop
        if (kc < 3) {
            #pragma unroll
            for (int r = 0; r < 8; ++r) {
                int g = t + r * 256;
                int k = g >> 6, cch = g & 63;
                xreg[r] = *(const float4*)&xbase[(size_t)((kc + 1) * 32 + k) * kHW + cch * 4];
            }
        }
        #pragma unroll 4
        for (int k = 0; k < 32; ++k) {
            const float* wr = wT + (size_t)(kc * 32 + k) * 256 + ow;   // uniform -> s_load
            float4 w0 = *(const float4*)&wr[0];
            float4 w1 = *(const float4*)&wr[4];
            float4 w2 = *(const float4*)&wr[8];
            float4 w3 = *(const float4*)&wr[12];
            float4 xv = *(const float4*)&Xs[k * 256 + lane * 4];       // px 4*lane..+3
            float wv[16] = {w0.x, w0.y, w0.z, w0.w, w1.x, w1.y, w1.z, w1.w,
                            w2.x, w2.y, w2.z, w2.w, w3.x, w3.y, w3.z, w3.w};
            float xa[4] = {xv.x, xv.y, xv.z, xv.w};
            #pragma unroll
            for (int i = 0; i < 16; ++i)
                #pragma unroll
                for (int j = 0; j < 4; ++j)
                    acc[i][j] += wv[i] * xa[j];
        }
        __syncthreads();   // compute done reading Xs before next iter's ds_write
    }

    if (head < 2) {
        // per-lane horizontal pooling in registers, then LDS combine (r3-proven).
        float* Ps = &Xs[0];            // [o][r][m] : o*128 + r*32 + m  (32 KB)
        int r  = lane >> 4;            // image row within tile (0..3), 16 lanes/row
        int m0 = 2 * (lane & 15);      // first of 2 pool cells (px_in_row = 4*(lane&15))
        #pragma unroll
        for (int i = 0; i < 16; ++i) {
            int o = wvid * 16 + i;
            float bias = b_qkvl[ow + i];
            float y0 = gelu_exact(acc[i][0] + bias);
            float y1 = gelu_exact(acc[i][1] + bias);
            float y2 = gelu_exact(acc[i][2] + bias);
            float y3 = gelu_exact(acc[i][3] + bias);
            float s0, s1;
            if (head == 0) {           // 3-wide sums (pad-1 left), stride 2
                float left = __shfl_up(y3, 1);
                if ((lane & 15) == 0) left = 0.0f;
                s0 = left + y0 + y1;
                s1 = y1 + y2 + y3;
            } else {                   // 2-wide max, stride 2
                s0 = fmaxf(y0, y1);
                s1 = fmaxf(y2, y3);
            }
            Ps[o * 128 + r * 32 + m0]     = s0;
            Ps[o * 128 + r * 32 + m0 + 1] = s1;
        }
        __syncthreads();
        if (head == 0) {
            bool last = (pb == 15);
            for (int e = t; e < 2048; e += 256) {
                int o = e >> 5, m = e & 31;
                const float* P = &Ps[o * 128 + m];
                float pv0 = P[0], pv1 = P[32], pv2 = P[64], pv3 = P[96];
                float* dst = &qp[(((size_t)(b * kC4 + o)) << 10) + (2 * pb) * 32 + m];
                dst[32] = (pv1 + pv2 + pv3) * (1.0f / 9.0f);          // pool row 2pb+1: fully local
                atomicAdd(dst, (pv0 + pv1) * (1.0f / 9.0f));          // pool row 2pb
                if (!last) atomicAdd(dst + 64, pv3 * (1.0f / 9.0f));  // row r3 -> pool row 2pb+2
            }
        } else {
            for (int e = t; e < 2048; e += 256) {
                int o = e >> 5, m = e & 31;
                const float* P = &Ps[o * 128 + m];
                float* dst = &kp[(((size_t)(b * kC4 + o)) << 10) + (2 * pb) * 32 + m];
                dst[0]  = fmaxf(P[0],  P[32]);
                dst[32] = fmaxf(P[64], P[96]);
            }
        }
    } else {
        // v (head2: o 128..191 -> out ch 192..255), lfeat (head3: o 192..255 -> out ch 128..191)
        #pragma unroll
        for (int i = 0; i < 16; ++i) {
            int og  = ow + i;
            int och = (head == 2) ? (og + 64) : (og - 64);
            float bias = b_qkvl[og];
            float4 y = make_float4(gelu_exact(acc[i][0] + bias), gelu_exact(acc[i][1] + bias),
                                   gelu_exact(acc[i][2] + bias), gelu_exact(acc[i][3] + bias));
            *(float4*)&out[(size_t)(b * kC + och) * kHW + p0 + lane * 4] = y;
        }
    }
}

// ---------------- Kernel 3a: partial qk[c][d] += sum_{n-chunk} qf[c][n] kf[d][n] ----------------
__global__ __launch_bounds__(256) void qk_partial_kernel(
    const float* __restrict__ qp, const float* __restrict__ kp,
    float* __restrict__ qkb)
{
    __shared__ float qsT[128][65];   // [n][c] 33.3 KB
    __shared__ float ksT[128][65];   // [n][d] 33.3 KB
    int nb = blockIdx.x;             // n-chunk
    int b  = blockIdx.y;
    int t  = threadIdx.x;
    int tc = t & 15;                 // c-tile: c = tc*4+i
    int td = t >> 4;                 // d-tile: d = td*4+j

    #pragma unroll
    for (int r = 0; r < 8; ++r) {
        int g = t + r * 256;         // 0..2047
        int ch = g >> 5, n4 = g & 31;
        float4 q4 = *(const float4*)&qp[(size_t)(b * 64 + ch) * 1024 + nb * 128 + n4 * 4];
        qsT[n4 * 4 + 0][ch] = q4.x;
        qsT[n4 * 4 + 1][ch] = q4.y;
        qsT[n4 * 4 + 2][ch] = q4.z;
        qsT[n4 * 4 + 3][ch] = q4.w;
        float4 k4 = *(const float4*)&kp[(size_t)(b * 64 + ch) * 1024 + nb * 128 + n4 * 4];
        ksT[n4 * 4 + 0][ch] = k4.x;
        ksT[n4 * 4 + 1][ch] = k4.y;
        ksT[n4 * 4 + 2][ch] = k4.z;
        ksT[n4 * 4 + 3][ch] = k4.w;
    }
    __syncthreads();

    float acc[4][4] = {};
    #pragma unroll 4
    for (int n = 0; n < 128; ++n) {
        float4 q4 = *(const float4*)&qsT[n][tc * 4];
        float4 k4 = *(const float4*)&ksT[n][td * 4];
        float qa[4] = {q4.x, q4.y, q4.z, q4.w};
        float ka[4] = {k4.x, k4.y, k4.z, k4.w};
        #pragma unroll
        for (int i = 0; i < 4; ++i)
            #pragma unroll
            for (int j = 0; j < 4; ++j)
                acc[i][j] += qa[i] * ka[j];
    }
    #pragma unroll
    for (int i = 0; i < 4; ++i)
        #pragma unroll
        for (int j = 0; j < 4; ++j)
            atomicAdd(&qkb[((size_t)b * 64 + tc * 4 + i) * 64 + td * 4 + j], acc[i][j]);
}

// ---------------- Kernel 3b: softmax over c per (b, d) ----------------
__global__ __launch_bounds__(256) void softmax_kernel(
    const float* __restrict__ qkb, float* __restrict__ attn)
{
    __shared__ float qk_s[64][65];
    __shared__ float mxs[64], sms[64];
    int b = blockIdx.x;
    int t = threadIdx.x;
    #pragma unroll
    for (int r = 0; r < 16; ++r) {
        int g = t + r * 256;
        qk_s[g >> 6][g & 63] = qkb[(size_t)b * 4096 + g];
    }
    __syncthreads();
    if (t < 64) {
        float m = -1e30f;
        #pragma unroll 4
        for (int cc = 0; cc < 64; ++cc) m = fmaxf(m, qk_s[cc][t]);
        float s = 0.f;
        #pragma unroll 4
        for (int cc = 0; cc < 64; ++cc) s += expf(qk_s[cc][t] - m);
        mxs[t] = m;
        sms[t] = 1.0f / s;
    }
    __syncthreads();
    #pragma unroll
    for (int r = 0; r < 16; ++r) {
        int g = t + r * 256;
        int c = g >> 6, d = g & 63;
        attn[(size_t)b * 4096 + g] = expf(qk_s[c][d] - mxs[d]) * sms[d];
    }
}

// ---------------- Kernel 4: out[b,192+d,m] = sum_c attn[b,c,d] * v[b,c,m] ----------------
// attn rows block-uniform -> SCALAR loads. v loads in 8-wide chunks so 8 strided
// loads are in flight per 512 FMA (latency hidden); all indexing static.
__global__ __launch_bounds__(256) void out2_kernel(
    const float* __restrict__ attn, float* __restrict__ out)
{
    int b = blockIdx.y;
    int t = threadIdx.x;
    int m = blockIdx.x * 256 + t;
    float* vcol = out + (size_t)(b * kC + 192) * kHW + m;   // stride kHW per channel
    const float* ar = attn + (size_t)b * 4096;              // uniform rows -> s_load
    float acc[64] = {};
    for (int c8 = 0; c8 < 8; ++c8) {
        float v[8];
        #pragma unroll
        for (int j = 0; j < 8; ++j) v[j] = vcol[(size_t)(c8 * 8 + j) * kHW];
        #pragma unroll
        for (int j = 0; j < 8; ++j) {
            float vv = v[j];
            const float* arow = ar + (c8 * 8 + j) * 64;
            #pragma unroll
            for (int d = 0; d < 64; ++d)
                acc[d] += arow[d] * vv;
        }
    }
    #pragma unroll
    for (int d = 0; d < 64; ++d)
        vcol[(size_t)d * kHW] = acc[d];
}

extern "C" void kernel_launch(void* const* d_in, const int* in_sizes, int n_in,
                              void* d_out, int out_size, void* d_ws, size_t ws_size,
                              hipStream_t stream)
{
    const float* x      = (const float*)d_in[0];
    const float* w_hw   = (const float*)d_in[1];
    const float* b_hw   = (const float*)d_in[2];
    const float* w_w    = (const float*)d_in[3];
    const float* b_w    = (const float*)d_in[4];
    const float* w_h    = (const float*)d_in[5];
    const float* b_h    = (const float*)d_in[6];
    const float* w_qkvl = (const float*)d_in[7];
    const float* b_qkvl = (const float*)d_in[8];
    float* out = (float*)d_out;

    // Workspace (17.83 MB, exact r5-verified layout): qp | kp | attn | qkb.
    // wT (128 KB) ALIASES attn: wT is consumed by conv1x1, attn is first
    // written by softmax_kernel (two launches later) -> disjoint lifetimes.
    char* w = (char*)d_ws;
    float* qp   = (float*)w;  w += (size_t)kB * kC4 * 1024 * 4;   // 8.39 MB (atomic-accum)
    float* kp   = (float*)w;  w += (size_t)kB * kC4 * 1024 * 4;   // 8.39 MB (fully written)
    float* attn = (float*)w;  w += (size_t)kB * kC4 * kC4 * 4;    // 0.52 MB
    float* qkb  = (float*)w;  w += (size_t)kB * kC4 * kC4 * 4;    // 0.52 MB (atomic-accum)
    float* wT   = attn;                                           // 0.13 MB, lifetime-disjoint

    init_kernel<<<dim3(2176), 256, 0, stream>>>((float4*)qp, (float4*)qkb);
    wt_kernel<<<dim3(16), 256, 0, stream>>>(w_qkvl, wT);
    part1_kernel<<<dim3(kB * 128), 256, 0, stream>>>(x, w_hw, b_hw, w_w, b_w, w_h, b_h, out);
    conv1x1_kernel<<<dim3(16, 4, kB), 256, 0, stream>>>(x, wT, b_qkvl, qp, kp, out);
    qk_partial_kernel<<<dim3(8, kB), 256, 0, stream>>>(qp, kp, qkb);
    softmax_kernel<<<dim3(kB), 256, 0, stream>>>(qkb, attn);
    out2_kernel<<<dim3(16, kB), 256, 0, stream>>>(attn, out);
}